// Round 4
// baseline (951.140 us; speedup 1.0000x reference)
//
#include <hip/hip_runtime.h>
#include <hip/hip_bf16.h>

#define NFEAT 300
#define KP 320           // padded feature stride (bf16 rows)
#define NGRAPH 2048
#define N1P 640          // padded N for GEMM1 (600 -> 640)
#define N2P 384          // padded N for GEMM2 (300 -> 384)
#define NTD 18           // bond_type(6) * bond_dir(3)
#define SCAN_B 2048      // elements per scan block (256 thr * 8)

typedef __bf16 bf16x8 __attribute__((ext_vector_type(8)));
typedef float  f32x4  __attribute__((ext_vector_type(4)));
typedef unsigned short u16x8 __attribute__((ext_vector_type(8)));

__device__ __forceinline__ unsigned short f2b(float v) {
    union { float f; unsigned u; } x; x.f = v;
    unsigned r = x.u + 0x7fff + ((x.u >> 16) & 1);   // RNE
    return (unsigned short)(r >> 16);
}
__device__ __forceinline__ float b2f(unsigned short u) {
    union { unsigned u; float f; } x; x.u = ((unsigned)u) << 16;
    return x.f;
}

#define GLD_LDS16(g, l)                                                        \
    __builtin_amdgcn_global_load_lds(                                          \
        (const __attribute__((address_space(1))) void*)(g),                    \
        (__attribute__((address_space(3))) void*)(l), 16, 0, 0)

// ---------------------------------------------------------------------------
// embc[td][c] = emb1[td/3][c] + emb2[td%3][c]  (fp32, [18 x 320], pad cols 0)
// ---------------------------------------------------------------------------
__global__ __launch_bounds__(256) void k_embc(
    const float* __restrict__ emb1, const float* __restrict__ emb2,
    float* __restrict__ embc)
{
    int t = blockIdx.x * blockDim.x + threadIdx.x;
    if (t >= NTD * KP) return;
    int td = t / KP, c = t % KP;
    int t1 = td / 3, d = td % 3;
    embc[t] = (c < NFEAT) ? emb1[t1 * NFEAT + c] + emb2[d * NFEAT + c] : 0.f;
}

// ---------------------------------------------------------------------------
// x fp32 [n x 300] -> xb bf16 [Mpad x 320] (pads zero)
// ---------------------------------------------------------------------------
__global__ __launch_bounds__(256) void k_cvtX(
    const float* __restrict__ x, unsigned short* __restrict__ xb, int n, int Mpad)
{
    int idx = blockIdx.x * blockDim.x + threadIdx.x;
    if (idx >= Mpad * (KP / 8)) return;
    int row = idx / (KP / 8), c0 = (idx % (KP / 8)) * 8;
    unsigned short o[8];
#pragma unroll
    for (int j = 0; j < 8; ++j) {
        int col = c0 + j;
        float v = (row < n && col < NFEAT) ? x[(size_t)row * NFEAT + col] : 0.f;
        o[j] = f2b(v);
    }
    *(uint4*)&xb[(size_t)row * KP + c0] = *(uint4*)o;
}

// ---------------------------------------------------------------------------
// CSR build: deg -> exclusive-scan offsets -> cursor fill, packed records
// ---------------------------------------------------------------------------
__global__ __launch_bounds__(256) void k_zero(int* __restrict__ p, int n)
{
    int i = blockIdx.x * blockDim.x + threadIdx.x;
    if (i < n) p[i] = 0;
}

__global__ __launch_bounds__(256) void k_deg(
    const int* __restrict__ ei, int* __restrict__ deg, int E)
{
    int e = blockIdx.x * blockDim.x + threadIdx.x;
    if (e >= E) return;
    atomicAdd(&deg[ei[E + e]], 1);
}

__global__ __launch_bounds__(256) void k_scan1(
    const int* __restrict__ deg, int* __restrict__ offsets,
    int* __restrict__ bsum, int n)
{
    __shared__ int sh[256];
    int tid = threadIdx.x;
    int base = blockIdx.x * SCAN_B + tid * 8;
    int v[8], run = 0;
#pragma unroll
    for (int j = 0; j < 8; ++j) {
        int i = base + j;
        v[j] = (i < n) ? deg[i] : 0;
        run += v[j];
        v[j] = run;
    }
    sh[tid] = run;
    __syncthreads();
    for (int off = 1; off < 256; off <<= 1) {
        int t = (tid >= off) ? sh[tid - off] : 0;
        __syncthreads();
        sh[tid] += t;
        __syncthreads();
    }
    int excl = sh[tid] - run;
#pragma unroll
    for (int j = 0; j < 8; ++j) {
        int i = base + j;
        if (i < n) offsets[i + 1] = excl + v[j];
    }
    if (tid == 0) bsum[blockIdx.x] = sh[255];
}

__global__ void k_scan2(int* __restrict__ bsum, int nb, int* __restrict__ offsets)
{
    if (threadIdx.x == 0 && blockIdx.x == 0) {
        int run = 0;
        for (int b = 0; b < nb; ++b) { int t = bsum[b]; bsum[b] = run; run += t; }
        offsets[0] = 0;
    }
}

__global__ __launch_bounds__(256) void k_scan3(
    const int* __restrict__ deg, int* __restrict__ offsets,
    const int* __restrict__ bsum, int* __restrict__ cursor, int n)
{
    int i = blockIdx.x * blockDim.x + threadIdx.x;
    if (i >= n) return;
    int fin = offsets[i + 1] + bsum[i / SCAN_B];
    offsets[i + 1] = fin;
    cursor[i] = fin - deg[i];
}

__global__ __launch_bounds__(256) void k_fill(
    const int* __restrict__ ei, const int* __restrict__ ea,
    int* __restrict__ cursor, int* __restrict__ edgerec, int E)
{
    int e = blockIdx.x * blockDim.x + threadIdx.x;
    if (e >= E) return;
    int dst = ei[E + e];
    int pos = atomicAdd(&cursor[dst], 1);
    int src = ei[e];
    int td  = ea[2 * e] * 3 + ea[2 * e + 1];
    edgerec[pos] = src | (td << 20);
}

// ---------------------------------------------------------------------------
// Gather-side aggregation:
// Ab[v] = bf16( h[v] + embc[0] + sum_{e: dst=v} ( h[src_e] + embc[td_e] ) )
// ---------------------------------------------------------------------------
__global__ __launch_bounds__(256) void k_aggr(
    const unsigned short* __restrict__ h,
    const int* __restrict__ offsets, const int* __restrict__ edgerec,
    const float* __restrict__ embc,
    unsigned short* __restrict__ Ab, int n, int Mpad)
{
    int idx = blockIdx.x * blockDim.x + threadIdx.x;
    if (idx >= Mpad * (KP / 8)) return;
    int v = idx / (KP / 8), c0 = (idx % (KP / 8)) * 8;
    unsigned short* outp = &Ab[(size_t)v * KP + c0];
    if (v >= n) {
        *(uint4*)outp = make_uint4(0, 0, 0, 0);
        return;
    }
    float acc[8];
    u16x8 hv = *(const u16x8*)&h[(size_t)v * KP + c0];
    const float* e0 = embc + c0;
#pragma unroll
    for (int j = 0; j < 8; ++j) acc[j] = b2f(hv[j]) + e0[j];

    int beg = offsets[v], end = offsets[v + 1];
    for (int e = beg; e < end; ++e) {
        int rec = edgerec[e];
        int src = rec & 0xFFFFF;
        int td  = rec >> 20;
        u16x8 hs = *(const u16x8*)&h[(size_t)src * KP + c0];
        const float* ee = embc + td * KP + c0;
#pragma unroll
        for (int j = 0; j < 8; ++j) acc[j] += b2f(hs[j]) + ee[j];
    }
    unsigned short o[8];
#pragma unroll
    for (int j = 0; j < 8; ++j) o[j] = f2b(acc[j]);
    *(uint4*)outp = *(uint4*)o;
}

// ---------------------------------------------------------------------------
// Wt[n*Kpad + k] = bf16(W[k*cols + n]) if in range else 0
// ---------------------------------------------------------------------------
__global__ __launch_bounds__(256) void k_cvtW(
    const float* __restrict__ W, unsigned short* __restrict__ Wt,
    int rows, int cols, int Kpad, int Npad)
{
    int t = blockIdx.x * blockDim.x + threadIdx.x;
    if (t >= Npad * Kpad) return;
    int nn = t / Kpad, k = t % Kpad;
    float v = (k < rows && nn < cols) ? W[(size_t)k * cols + nn] : 0.f;
    Wt[t] = f2b(v);
}

// ---------------------------------------------------------------------------
// bf16 MFMA GEMM, panel-resident version:
// grid.x = M/128 row-panels. Each block loops over ALL npass N-tiles of 128,
// so its A-panel is fetched from HBM once and re-read from L2 on later passes.
// Epilogue bounces through LDS (64-col chunks) for coalesced uint4 stores.
// C = relu(A @ Bt^T + bias). A [Mpad x K] rm bf16, Bt [N x K] rm bf16.
// LDS 16 KB: sA = smem[0:4096], sB = smem[4096:8192] (128x32 each).
// ---------------------------------------------------------------------------
__global__ __launch_bounds__(256) void k_gemm(
    const unsigned short* __restrict__ Ag, const unsigned short* __restrict__ Bg,
    const float* __restrict__ bias, int bias_n,
    unsigned short* __restrict__ C, int ldc, int store_cols,
    int K, int npass)
{
    __shared__ unsigned short smem[8192];   // 16 KB, staged tiles / epilogue

    int tid  = threadIdx.x;
    int wave = tid >> 6, lane = tid & 63;
    int m0 = blockIdx.x * 128;
    int wm = (wave >> 1) * 64, wn = (wave & 1) * 64;

    int mrow = lane & 15;
    int kq   = (lane >> 4) * 8;
    int colq = lane & 15, rq = (lane >> 4) * 4;

    const unsigned short* Abase = Ag + (size_t)m0 * K;

    for (int n0 = 0; n0 < npass; ++n0) {
        const unsigned short* Bbase = Bg + (size_t)n0 * 128 * K;

        f32x4 acc[4][4];
#pragma unroll
        for (int i = 0; i < 4; ++i)
#pragma unroll
            for (int j = 0; j < 4; ++j)
                acc[i][j] = (f32x4){0.f, 0.f, 0.f, 0.f};

        int row_l = tid >> 2;          // 0..63 (+64 on second issue)
        int k8    = (tid & 3) * 8;

        for (int k0 = 0; k0 < K; k0 += 32) {
            GLD_LDS16(Abase + (size_t)row_l * K + k0 + k8,        &smem[tid * 8]);
            GLD_LDS16(Abase + (size_t)(row_l + 64) * K + k0 + k8, &smem[(256 + tid) * 8]);
            GLD_LDS16(Bbase + (size_t)row_l * K + k0 + k8,        &smem[4096 + tid * 8]);
            GLD_LDS16(Bbase + (size_t)(row_l + 64) * K + k0 + k8, &smem[4096 + (256 + tid) * 8]);
            __syncthreads();

            bf16x8 af[4], bfv[4];
#pragma unroll
            for (int i = 0; i < 4; ++i) {
                af[i]  = *(const bf16x8*)&smem[(wm + i * 16 + mrow) * 32 + kq];
                bfv[i] = *(const bf16x8*)&smem[4096 + (wn + i * 16 + mrow) * 32 + kq];
            }
#pragma unroll
            for (int i = 0; i < 4; ++i)
#pragma unroll
                for (int j = 0; j < 4; ++j)
                    acc[i][j] = __builtin_amdgcn_mfma_f32_16x16x32_bf16(
                        af[i], bfv[j], acc[i][j], 0, 0, 0);
            __syncthreads();
        }

        // ---- epilogue: bias + relu + bf16, LDS bounce for coalesced stores
        // chunk ch covers global cols [n0*128 + ch*64, +64)
#pragma unroll
        for (int ch = 0; ch < 2; ++ch) {
            if ((wn >> 6) == ch) {          // waves owning this 64-col half
#pragma unroll
                for (int j = 0; j < 4; ++j) {
                    int lc  = j * 16 + colq;                 // 0..63
                    int col = n0 * 128 + wn + j * 16 + colq; // global col
                    float bv = (col < bias_n) ? bias[col] : 0.f;
#pragma unroll
                    for (int i = 0; i < 4; ++i) {
                        int rbase = wm + i * 16 + rq;
#pragma unroll
                        for (int r = 0; r < 4; ++r) {
                            float v = fmaxf(acc[i][j][r] + bv, 0.f);
                            smem[(rbase + r) * 64 + lc] = f2b(v);
                        }
                    }
                }
            }
            __syncthreads();
            int cbase = n0 * 128 + ch * 64;
            if (cbase < store_cols) {
#pragma unroll
                for (int i = 0; i < 4; ++i) {
                    int idx = i * 256 + tid;        // 0..1023 uint4 chunks
                    int row = idx >> 3, c8 = idx & 7;
                    *(uint4*)&C[(size_t)(m0 + row) * ldc + cbase + c8 * 8] =
                        *(uint4*)&smem[row * 64 + c8 * 8];
                }
            }
            __syncthreads();
        }
    }
}

// ---------------------------------------------------------------------------
// pool: g[gid] = sum of Hb rows (bf16, stride KP) with batch==gid (sorted)
// ---------------------------------------------------------------------------
__global__ __launch_bounds__(256) void k_pool(
    const unsigned short* __restrict__ H, const int* __restrict__ batch,
    float* __restrict__ g, int n)
{
    int gid = blockIdx.x;
    int lo = 0, hi = n;
    while (lo < hi) { int mid = (lo + hi) >> 1; if (batch[mid] < gid) lo = mid + 1; else hi = mid; }
    int start = lo;
    hi = n;
    while (lo < hi) { int mid = (lo + hi) >> 1; if (batch[mid] < gid + 1) lo = mid + 1; else hi = mid; }
    int end = lo;

    for (int f = threadIdx.x; f < NFEAT; f += blockDim.x) {
        float acc = 0.f;
        for (int v = start; v < end; ++v) acc += b2f(H[(size_t)v * KP + f]);
        g[(size_t)gid * NFEAT + f] = acc;
    }
}

// ---------------------------------------------------------------------------
// out = g @ Wfc + bfc   (2048x300 @ 300x300), fp32
// ---------------------------------------------------------------------------
__global__ __launch_bounds__(256) void k_final(
    const float* __restrict__ g, const float* __restrict__ Wfc,
    const float* __restrict__ bfc, float* __restrict__ out)
{
    int idx = blockIdx.x * blockDim.x + threadIdx.x;
    if (idx >= NGRAPH * NFEAT) return;
    int r = idx / NFEAT, c = idx % NFEAT;
    float acc = bfc[c];
    for (int k = 0; k < NFEAT; ++k)
        acc = fmaf(g[(size_t)r * NFEAT + k], Wfc[(size_t)k * NFEAT + c], acc);
    out[idx] = acc;
}

extern "C" void kernel_launch(void* const* d_in, const int* in_sizes, int n_in,
                              void* d_out, int out_size, void* d_ws, size_t ws_size,
                              hipStream_t stream)
{
    const float* x    = (const float*)d_in[0];
    const int*   ei   = (const int*)  d_in[1];
    const int*   ea   = (const int*)  d_in[2];
    const int*   batch= (const int*)  d_in[3];
    const float* emb1 = (const float*)d_in[4];
    const float* emb2 = (const float*)d_in[5];
    const float* W1   = (const float*)d_in[6];
    const float* b1   = (const float*)d_in[7];
    const float* W2   = (const float*)d_in[8];
    const float* b2   = (const float*)d_in[9];
    const float* Wfc  = (const float*)d_in[10];
    const float* bfc  = (const float*)d_in[11];
    float* out = (float*)d_out;

    int n = in_sizes[0] / NFEAT;   // 100000
    int E = in_sizes[1] / 2;       // 200000
    int MT   = (n + 127) / 128;    // 782
    int Mpad = MT * 128;           // 100096

    // ---- workspace layout ----
    char* p = (char*)d_ws;
    auto take = [&](size_t bytes) { char* r = p; p += (bytes + 255) & ~(size_t)255; return r; };
    unsigned short* T    = (unsigned short*)take((size_t)Mpad * N1P * 2); // 128.1 MB
    unsigned short* xb   = T;                                             // overlay (dead before T)
    unsigned short* Ab   = (unsigned short*)take((size_t)Mpad * KP * 2);  // 64.06 MB
    unsigned short* Hb   = (unsigned short*)take((size_t)Mpad * KP * 2);  // 64.06 MB
    unsigned short* Wt1  = (unsigned short*)take((size_t)N1P * KP * 2);
    unsigned short* Wt2  = (unsigned short*)take((size_t)N2P * N1P * 2);
    float*          embc = (float*)take((size_t)NTD * KP * 4);
    float*          g    = (float*)take((size_t)NGRAPH * NFEAT * 4);
    int*            deg  = (int*)take((size_t)n * 4);
    int*            offs = (int*)take((size_t)(n + 1) * 4);
    int*            curs = (int*)take((size_t)n * 4);
    int*            erec = (int*)take((size_t)E * 4);
    int*            bsum = (int*)take(256 * 4);

    dim3 blk(256);
    int chunkThreads = Mpad * (KP / 8);
    int chunkBlocks  = (chunkThreads + 255) / 256;
    int nb = (n + SCAN_B - 1) / SCAN_B;

    // ---- one-time prep (per call) ----
    k_cvtW<<<(N1P * KP + 255) / 256, blk, 0, stream>>>(W1, Wt1, NFEAT, 600, KP, N1P);
    k_cvtW<<<(N2P * N1P + 255) / 256, blk, 0, stream>>>(W2, Wt2, 600, NFEAT, N1P, N2P);
    k_embc<<<(NTD * KP + 255) / 256, blk, 0, stream>>>(emb1, emb2, embc);
    k_cvtX<<<chunkBlocks, blk, 0, stream>>>(x, xb, n, Mpad);

    // ---- CSR build ----
    k_zero <<<(n + 255) / 256, blk, 0, stream>>>(deg, n);
    k_deg  <<<(E + 255) / 256, blk, 0, stream>>>(ei, deg, E);
    k_scan1<<<nb, blk, 0, stream>>>(deg, offs, bsum, n);
    k_scan2<<<1, 64, 0, stream>>>(bsum, nb, offs);
    k_scan3<<<(n + 255) / 256, blk, 0, stream>>>(deg, offs, bsum, curs, n);
    k_fill <<<(E + 255) / 256, blk, 0, stream>>>(ei, ea, curs, erec, E);

    // ---- layer 1 ----
    k_aggr<<<chunkBlocks, blk, 0, stream>>>(xb, offs, erec, embc, Ab, n, Mpad);
    k_gemm<<<MT, blk, 0, stream>>>(Ab, Wt1, b1, 600, T, N1P, N1P, KP, N1P / 128);
    k_gemm<<<MT, blk, 0, stream>>>(T, Wt2, b2, NFEAT, Hb, KP, KP, N1P, N2P / 128);

    // ---- layer 2 ----
    k_aggr<<<chunkBlocks, blk, 0, stream>>>(Hb, offs, erec, embc, Ab, n, Mpad);
    k_gemm<<<MT, blk, 0, stream>>>(Ab, Wt1, b1, 600, T, N1P, N1P, KP, N1P / 128);
    k_gemm<<<MT, blk, 0, stream>>>(T, Wt2, b2, NFEAT, Hb, KP, KP, N1P, N2P / 128);

    // ---- pool + final ----
    k_pool <<<NGRAPH, blk, 0, stream>>>(Hb, batch, g, n);
    k_final<<<(NGRAPH * NFEAT + 255) / 256, blk, 0, stream>>>(g, Wfc, bfc, out);
}

// Round 5
// 871.338 us; speedup vs baseline: 1.0916x; 1.0916x over previous
//
#include <hip/hip_runtime.h>
#include <hip/hip_bf16.h>

#define NFEAT 300
#define KP 320           // padded feature stride (bf16 rows)
#define NGRAPH 2048
#define N1P 640          // padded N for GEMM1 (600 -> 640)
#define N2P 384          // padded N for GEMM2 (300 -> 384)
#define NTD 18           // bond_type(6) * bond_dir(3)
#define SCAN_B 2048      // elements per scan block (256 thr * 8)

typedef __bf16 bf16x8 __attribute__((ext_vector_type(8)));
typedef float  f32x4  __attribute__((ext_vector_type(4)));
typedef unsigned short u16x8 __attribute__((ext_vector_type(8)));

__device__ __forceinline__ unsigned short f2b(float v) {
    union { float f; unsigned u; } x; x.f = v;
    unsigned r = x.u + 0x7fff + ((x.u >> 16) & 1);   // RNE
    return (unsigned short)(r >> 16);
}
__device__ __forceinline__ float b2f(unsigned short u) {
    union { unsigned u; float f; } x; x.u = ((unsigned)u) << 16;
    return x.f;
}

#define GLD_LDS16(g, l)                                                        \
    __builtin_amdgcn_global_load_lds(                                          \
        (const __attribute__((address_space(1))) void*)(g),                    \
        (__attribute__((address_space(3))) void*)(l), 16, 0, 0)

// ---------------------------------------------------------------------------
// embc[td][c] = emb1[td/3][c] + emb2[td%3][c]  (fp32, [18 x 320], pad cols 0)
// ---------------------------------------------------------------------------
__global__ __launch_bounds__(256) void k_embc(
    const float* __restrict__ emb1, const float* __restrict__ emb2,
    float* __restrict__ embc)
{
    int t = blockIdx.x * blockDim.x + threadIdx.x;
    if (t >= NTD * KP) return;
    int td = t / KP, c = t % KP;
    int t1 = td / 3, d = td % 3;
    embc[t] = (c < NFEAT) ? emb1[t1 * NFEAT + c] + emb2[d * NFEAT + c] : 0.f;
}

// ---------------------------------------------------------------------------
// x fp32 [n x 300] -> xb bf16 [Mpad x 320] (pads zero)
// ---------------------------------------------------------------------------
__global__ __launch_bounds__(256) void k_cvtX(
    const float* __restrict__ x, unsigned short* __restrict__ xb, int n, int Mpad)
{
    int idx = blockIdx.x * blockDim.x + threadIdx.x;
    if (idx >= Mpad * (KP / 8)) return;
    int row = idx / (KP / 8), c0 = (idx % (KP / 8)) * 8;
    unsigned short o[8];
#pragma unroll
    for (int j = 0; j < 8; ++j) {
        int col = c0 + j;
        float v = (row < n && col < NFEAT) ? x[(size_t)row * NFEAT + col] : 0.f;
        o[j] = f2b(v);
    }
    *(uint4*)&xb[(size_t)row * KP + c0] = *(uint4*)o;
}

// ---------------------------------------------------------------------------
// CSR build: deg -> exclusive-scan offsets -> cursor fill, packed records
// ---------------------------------------------------------------------------
__global__ __launch_bounds__(256) void k_zero(int* __restrict__ p, int n)
{
    int i = blockIdx.x * blockDim.x + threadIdx.x;
    if (i < n) p[i] = 0;
}

__global__ __launch_bounds__(256) void k_deg(
    const int* __restrict__ ei, int* __restrict__ deg, int E)
{
    int e = blockIdx.x * blockDim.x + threadIdx.x;
    if (e >= E) return;
    atomicAdd(&deg[ei[E + e]], 1);
}

__global__ __launch_bounds__(256) void k_scan1(
    const int* __restrict__ deg, int* __restrict__ offsets,
    int* __restrict__ bsum, int n)
{
    __shared__ int sh[256];
    int tid = threadIdx.x;
    int base = blockIdx.x * SCAN_B + tid * 8;
    int v[8], run = 0;
#pragma unroll
    for (int j = 0; j < 8; ++j) {
        int i = base + j;
        v[j] = (i < n) ? deg[i] : 0;
        run += v[j];
        v[j] = run;
    }
    sh[tid] = run;
    __syncthreads();
    for (int off = 1; off < 256; off <<= 1) {
        int t = (tid >= off) ? sh[tid - off] : 0;
        __syncthreads();
        sh[tid] += t;
        __syncthreads();
    }
    int excl = sh[tid] - run;
#pragma unroll
    for (int j = 0; j < 8; ++j) {
        int i = base + j;
        if (i < n) offsets[i + 1] = excl + v[j];
    }
    if (tid == 0) bsum[blockIdx.x] = sh[255];
}

__global__ void k_scan2(int* __restrict__ bsum, int nb, int* __restrict__ offsets)
{
    if (threadIdx.x == 0 && blockIdx.x == 0) {
        int run = 0;
        for (int b = 0; b < nb; ++b) { int t = bsum[b]; bsum[b] = run; run += t; }
        offsets[0] = 0;
    }
}

__global__ __launch_bounds__(256) void k_scan3(
    const int* __restrict__ deg, int* __restrict__ offsets,
    const int* __restrict__ bsum, int* __restrict__ cursor, int n)
{
    int i = blockIdx.x * blockDim.x + threadIdx.x;
    if (i >= n) return;
    int fin = offsets[i + 1] + bsum[i / SCAN_B];
    offsets[i + 1] = fin;
    cursor[i] = fin - deg[i];
}

__global__ __launch_bounds__(256) void k_fill(
    const int* __restrict__ ei, const int* __restrict__ ea,
    int* __restrict__ cursor, int* __restrict__ edgerec, int E)
{
    int e = blockIdx.x * blockDim.x + threadIdx.x;
    if (e >= E) return;
    int dst = ei[E + e];
    int pos = atomicAdd(&cursor[dst], 1);
    int src = ei[e];
    int td  = ea[2 * e] * 3 + ea[2 * e + 1];
    edgerec[pos] = src | (td << 20);
}

// ---------------------------------------------------------------------------
// Gather-side aggregation:
// Ab[v] = bf16( h[v] + embc[0] + sum_{e: dst=v} ( h[src_e] + embc[td_e] ) )
// ---------------------------------------------------------------------------
__global__ __launch_bounds__(256) void k_aggr(
    const unsigned short* __restrict__ h,
    const int* __restrict__ offsets, const int* __restrict__ edgerec,
    const float* __restrict__ embc,
    unsigned short* __restrict__ Ab, int n, int Mpad)
{
    int idx = blockIdx.x * blockDim.x + threadIdx.x;
    if (idx >= Mpad * (KP / 8)) return;
    int v = idx / (KP / 8), c0 = (idx % (KP / 8)) * 8;
    unsigned short* outp = &Ab[(size_t)v * KP + c0];
    if (v >= n) {
        *(uint4*)outp = make_uint4(0, 0, 0, 0);
        return;
    }
    float acc[8];
    u16x8 hv = *(const u16x8*)&h[(size_t)v * KP + c0];
    const float* e0 = embc + c0;
#pragma unroll
    for (int j = 0; j < 8; ++j) acc[j] = b2f(hv[j]) + e0[j];

    int beg = offsets[v], end = offsets[v + 1];
    for (int e = beg; e < end; ++e) {
        int rec = edgerec[e];
        int src = rec & 0xFFFFF;
        int td  = rec >> 20;
        u16x8 hs = *(const u16x8*)&h[(size_t)src * KP + c0];
        const float* ee = embc + td * KP + c0;
#pragma unroll
        for (int j = 0; j < 8; ++j) acc[j] += b2f(hs[j]) + ee[j];
    }
    unsigned short o[8];
#pragma unroll
    for (int j = 0; j < 8; ++j) o[j] = f2b(acc[j]);
    *(uint4*)outp = *(uint4*)o;
}

// ---------------------------------------------------------------------------
// Wt[n*Kpad + k] = bf16(W[k*cols + n]) if in range else 0
// ---------------------------------------------------------------------------
__global__ __launch_bounds__(256) void k_cvtW(
    const float* __restrict__ W, unsigned short* __restrict__ Wt,
    int rows, int cols, int Kpad, int Npad)
{
    int t = blockIdx.x * blockDim.x + threadIdx.x;
    if (t >= Npad * Kpad) return;
    int nn = t / Kpad, k = t % Kpad;
    float v = (k < rows && nn < cols) ? W[(size_t)k * cols + nn] : 0.f;
    Wt[t] = f2b(v);
}

// ---------------------------------------------------------------------------
// bf16 MFMA GEMM, grid-parallel + XCD-swizzled:
// grid = MT8 * npass 1-D blocks. Block mapping puts all npass N-tiles of a
// row-panel on the SAME XCD (linear%8 heuristic) so the A-panel is fetched
// from HBM once and served from that XCD's L2 for the other passes.
// LDS tiles are stored FRAGMENT-MAJOR: chunk c (16B) = [kgroup][row], so the
// ds_read_b128 fragment fetches are bank-conflict-free. Staging via
// global_load_lds picks the matching per-lane global address.
// Epilogue bounces accumulators through LDS for coalesced uint4 stores.
// C = relu(A @ Bt^T + bias). A [Mpad x K] rm bf16, Bt [N x K] rm bf16.
// ---------------------------------------------------------------------------
__global__ __launch_bounds__(256) void k_gemm(
    const unsigned short* __restrict__ Ag, const unsigned short* __restrict__ Bg,
    const float* __restrict__ bias, int bias_n,
    unsigned short* __restrict__ C, int ldc, int store_cols,
    int K, int npass, int MT)
{
    __shared__ unsigned short smem[8192];   // 16 KB: sA [0,4096), sB [4096,8192)

    int tid  = threadIdx.x;
    int lane = tid & 63, wave = tid >> 6;

    // XCD-swizzle: same panel -> same XCD for all npass column tiles
    int l    = blockIdx.x;
    int xcd  = l & 7;
    int j    = l >> 3;
    int ncol = j % npass;
    int panel= (j / npass) * 8 + xcd;
    if (panel >= MT) return;
    int m0 = panel * 128;

    int wm = (wave >> 1) * 64, wn = (wave & 1) * 64;
    int fr = lane & 15, fg = lane >> 4;          // fragment row / k-group
    int colq = lane & 15, rq = (lane >> 4) * 4;  // epilogue C/D mapping

    const unsigned short* Abase = Ag + (size_t)m0 * K;
    const unsigned short* Bbase = Bg + (size_t)ncol * 128 * K;

    // chunk ids for the two staging issues (c = kg*128 + row, kg = c>>7)
    int c0 = tid, c1 = 256 + tid;
    int r0 = c0 & 127, g0 = c0 >> 7;
    int r1 = c1 & 127, g1 = c1 >> 7;
    size_t aoff0 = (size_t)r0 * K + g0 * 8;
    size_t aoff1 = (size_t)r1 * K + g1 * 8;

    f32x4 acc[4][4];
#pragma unroll
    for (int i = 0; i < 4; ++i)
#pragma unroll
        for (int jj = 0; jj < 4; ++jj)
            acc[i][jj] = (f32x4){0.f, 0.f, 0.f, 0.f};

    for (int k0 = 0; k0 < K; k0 += 32) {
        GLD_LDS16(Abase + aoff0 + k0, &smem[c0 * 8]);
        GLD_LDS16(Abase + aoff1 + k0, &smem[c1 * 8]);
        GLD_LDS16(Bbase + aoff0 + k0, &smem[4096 + c0 * 8]);
        GLD_LDS16(Bbase + aoff1 + k0, &smem[4096 + c1 * 8]);
        __syncthreads();

        bf16x8 af[4], bfv[4];
#pragma unroll
        for (int i = 0; i < 4; ++i) {
            af[i]  = *(const bf16x8*)&smem[(fg * 128 + wm + i * 16 + fr) * 8];
            bfv[i] = *(const bf16x8*)&smem[4096 + (fg * 128 + wn + i * 16 + fr) * 8];
        }
#pragma unroll
        for (int i = 0; i < 4; ++i)
#pragma unroll
            for (int jj = 0; jj < 4; ++jj)
                acc[i][jj] = __builtin_amdgcn_mfma_f32_16x16x32_bf16(
                    af[i], bfv[jj], acc[i][jj], 0, 0, 0);
        __syncthreads();
    }

    // ---- epilogue: bias + relu + bf16, LDS bounce for coalesced stores ----
#pragma unroll
    for (int ch = 0; ch < 2; ++ch) {
        if ((wn >> 6) == ch) {              // waves owning this 64-col half
#pragma unroll
            for (int jj = 0; jj < 4; ++jj) {
                int lc  = jj * 16 + colq;                  // 0..63
                int col = ncol * 128 + wn + jj * 16 + colq;
                float bv = (col < bias_n) ? bias[col] : 0.f;
#pragma unroll
                for (int i = 0; i < 4; ++i) {
                    int rbase = wm + i * 16 + rq;
#pragma unroll
                    for (int r = 0; r < 4; ++r) {
                        float v = fmaxf(acc[i][jj][r] + bv, 0.f);
                        smem[(rbase + r) * 64 + lc] = f2b(v);
                    }
                }
            }
        }
        __syncthreads();
        int cbase = ncol * 128 + ch * 64;
        if (cbase < store_cols) {
#pragma unroll
            for (int i = 0; i < 4; ++i) {
                int idx = i * 256 + tid;        // 0..1023 uint4 chunks
                int row = idx >> 3, c8 = idx & 7;
                *(uint4*)&C[(size_t)(m0 + row) * ldc + cbase + c8 * 8] =
                    *(uint4*)&smem[row * 64 + c8 * 8];
            }
        }
        __syncthreads();
    }
}

// ---------------------------------------------------------------------------
// pool: g[gid] = sum of Hb rows (bf16, stride KP) with batch==gid (sorted)
// ---------------------------------------------------------------------------
__global__ __launch_bounds__(256) void k_pool(
    const unsigned short* __restrict__ H, const int* __restrict__ batch,
    float* __restrict__ g, int n)
{
    int gid = blockIdx.x;
    int lo = 0, hi = n;
    while (lo < hi) { int mid = (lo + hi) >> 1; if (batch[mid] < gid) lo = mid + 1; else hi = mid; }
    int start = lo;
    hi = n;
    while (lo < hi) { int mid = (lo + hi) >> 1; if (batch[mid] < gid + 1) lo = mid + 1; else hi = mid; }
    int end = lo;

    for (int f = threadIdx.x; f < NFEAT; f += blockDim.x) {
        float acc = 0.f;
        for (int v = start; v < end; ++v) acc += b2f(H[(size_t)v * KP + f]);
        g[(size_t)gid * NFEAT + f] = acc;
    }
}

// ---------------------------------------------------------------------------
// out = g @ Wfc + bfc   (2048x300 @ 300x300), fp32
// ---------------------------------------------------------------------------
__global__ __launch_bounds__(256) void k_final(
    const float* __restrict__ g, const float* __restrict__ Wfc,
    const float* __restrict__ bfc, float* __restrict__ out)
{
    int idx = blockIdx.x * blockDim.x + threadIdx.x;
    if (idx >= NGRAPH * NFEAT) return;
    int r = idx / NFEAT, c = idx % NFEAT;
    float acc = bfc[c];
    for (int k = 0; k < NFEAT; ++k)
        acc = fmaf(g[(size_t)r * NFEAT + k], Wfc[(size_t)k * NFEAT + c], acc);
    out[idx] = acc;
}

extern "C" void kernel_launch(void* const* d_in, const int* in_sizes, int n_in,
                              void* d_out, int out_size, void* d_ws, size_t ws_size,
                              hipStream_t stream)
{
    const float* x    = (const float*)d_in[0];
    const int*   ei   = (const int*)  d_in[1];
    const int*   ea   = (const int*)  d_in[2];
    const int*   batch= (const int*)  d_in[3];
    const float* emb1 = (const float*)d_in[4];
    const float* emb2 = (const float*)d_in[5];
    const float* W1   = (const float*)d_in[6];
    const float* b1   = (const float*)d_in[7];
    const float* W2   = (const float*)d_in[8];
    const float* b2   = (const float*)d_in[9];
    const float* Wfc  = (const float*)d_in[10];
    const float* bfc  = (const float*)d_in[11];
    float* out = (float*)d_out;

    int n = in_sizes[0] / NFEAT;   // 100000
    int E = in_sizes[1] / 2;       // 200000
    int MT   = (n + 127) / 128;    // 782
    int Mpad = MT * 128;           // 100096
    int MT8  = ((MT + 7) / 8) * 8; // 784 (XCD-swizzle padding)

    // ---- workspace layout ----
    char* p = (char*)d_ws;
    auto take = [&](size_t bytes) { char* r = p; p += (bytes + 255) & ~(size_t)255; return r; };
    unsigned short* T    = (unsigned short*)take((size_t)Mpad * N1P * 2); // 128.1 MB
    unsigned short* xb   = T;                                             // overlay (dead before T)
    unsigned short* Ab   = (unsigned short*)take((size_t)Mpad * KP * 2);  // 64.06 MB
    unsigned short* Hb   = (unsigned short*)take((size_t)Mpad * KP * 2);  // 64.06 MB
    unsigned short* Wt1  = (unsigned short*)take((size_t)N1P * KP * 2);
    unsigned short* Wt2  = (unsigned short*)take((size_t)N2P * N1P * 2);
    float*          embc = (float*)take((size_t)NTD * KP * 4);
    float*          g    = (float*)take((size_t)NGRAPH * NFEAT * 4);
    int*            deg  = (int*)take((size_t)n * 4);
    int*            offs = (int*)take((size_t)(n + 1) * 4);
    int*            curs = (int*)take((size_t)n * 4);
    int*            erec = (int*)take((size_t)E * 4);
    int*            bsum = (int*)take(256 * 4);

    dim3 blk(256);
    int chunkThreads = Mpad * (KP / 8);
    int chunkBlocks  = (chunkThreads + 255) / 256;
    int nb = (n + SCAN_B - 1) / SCAN_B;

    // ---- one-time prep (per call) ----
    k_cvtW<<<(N1P * KP + 255) / 256, blk, 0, stream>>>(W1, Wt1, NFEAT, 600, KP, N1P);
    k_cvtW<<<(N2P * N1P + 255) / 256, blk, 0, stream>>>(W2, Wt2, 600, NFEAT, N1P, N2P);
    k_embc<<<(NTD * KP + 255) / 256, blk, 0, stream>>>(emb1, emb2, embc);
    k_cvtX<<<chunkBlocks, blk, 0, stream>>>(x, xb, n, Mpad);

    // ---- CSR build ----
    k_zero <<<(n + 255) / 256, blk, 0, stream>>>(deg, n);
    k_deg  <<<(E + 255) / 256, blk, 0, stream>>>(ei, deg, E);
    k_scan1<<<nb, blk, 0, stream>>>(deg, offs, bsum, n);
    k_scan2<<<1, 64, 0, stream>>>(bsum, nb, offs);
    k_scan3<<<(n + 255) / 256, blk, 0, stream>>>(deg, offs, bsum, curs, n);
    k_fill <<<(E + 255) / 256, blk, 0, stream>>>(ei, ea, curs, erec, E);

    // ---- layer 1 ----
    k_aggr<<<chunkBlocks, blk, 0, stream>>>(xb, offs, erec, embc, Ab, n, Mpad);
    k_gemm<<<MT8 * (N1P / 128), blk, 0, stream>>>(Ab, Wt1, b1, 600, T, N1P, N1P, KP, N1P / 128, MT);
    k_gemm<<<MT8 * (N2P / 128), blk, 0, stream>>>(T, Wt2, b2, NFEAT, Hb, KP, KP, N1P, N2P / 128, MT);

    // ---- layer 2 ----
    k_aggr<<<chunkBlocks, blk, 0, stream>>>(Hb, offs, erec, embc, Ab, n, Mpad);
    k_gemm<<<MT8 * (N1P / 128), blk, 0, stream>>>(Ab, Wt1, b1, 600, T, N1P, N1P, KP, N1P / 128, MT);
    k_gemm<<<MT8 * (N2P / 128), blk, 0, stream>>>(T, Wt2, b2, NFEAT, Hb, KP, KP, N1P, N2P / 128, MT);

    // ---- pool + final ----
    k_pool <<<NGRAPH, blk, 0, stream>>>(Hb, batch, g, n);
    k_final<<<(NGRAPH * NFEAT + 255) / 256, blk, 0, stream>>>(g, Wfc, bfc, out);
}

// Round 6
// 750.288 us; speedup vs baseline: 1.2677x; 1.1613x over previous
//
#include <hip/hip_runtime.h>
#include <hip/hip_bf16.h>

#define NFEAT 300
#define KP 320           // padded feature stride (bf16 rows)
#define NGRAPH 2048
#define N1P 640          // padded N for GEMM1 (600 -> 640)
#define N2P 384          // padded N for GEMM2 (300 -> 384)
#define NTD 18           // bond_type(6) * bond_dir(3)
#define SCAN_B 2048      // elements per scan block (256 thr * 8)

typedef __bf16 bf16x8 __attribute__((ext_vector_type(8)));
typedef float  f32x4  __attribute__((ext_vector_type(4)));
typedef unsigned short u16x8 __attribute__((ext_vector_type(8)));

__device__ __forceinline__ unsigned short f2b(float v) {
    union { float f; unsigned u; } x; x.f = v;
    unsigned r = x.u + 0x7fff + ((x.u >> 16) & 1);   // RNE
    return (unsigned short)(r >> 16);
}
__device__ __forceinline__ float b2f(unsigned short u) {
    union { unsigned u; float f; } x; x.u = ((unsigned)u) << 16;
    return x.f;
}

#define GLD_LDS16(g, l)                                                        \
    __builtin_amdgcn_global_load_lds(                                          \
        (const __attribute__((address_space(1))) void*)(g),                    \
        (__attribute__((address_space(3))) void*)(l), 16, 0, 0)

// ---------------------------------------------------------------------------
// embc[td][c] = emb1[td/3][c] + emb2[td%3][c]  (fp32, [18 x 320], pad cols 0)
// ---------------------------------------------------------------------------
__global__ __launch_bounds__(256) void k_embc(
    const float* __restrict__ emb1, const float* __restrict__ emb2,
    float* __restrict__ embc)
{
    int t = blockIdx.x * blockDim.x + threadIdx.x;
    if (t >= NTD * KP) return;
    int td = t / KP, c = t % KP;
    int t1 = td / 3, d = td % 3;
    embc[t] = (c < NFEAT) ? emb1[t1 * NFEAT + c] + emb2[d * NFEAT + c] : 0.f;
}

// ---------------------------------------------------------------------------
// x fp32 [n x 300] -> xb bf16 [Mpad x 320] (pads zero)
// ---------------------------------------------------------------------------
__global__ __launch_bounds__(256) void k_cvtX(
    const float* __restrict__ x, unsigned short* __restrict__ xb, int n, int Mpad)
{
    int idx = blockIdx.x * blockDim.x + threadIdx.x;
    if (idx >= Mpad * (KP / 8)) return;
    int row = idx / (KP / 8), c0 = (idx % (KP / 8)) * 8;
    unsigned short o[8];
#pragma unroll
    for (int j = 0; j < 8; ++j) {
        int col = c0 + j;
        float v = (row < n && col < NFEAT) ? x[(size_t)row * NFEAT + col] : 0.f;
        o[j] = f2b(v);
    }
    *(uint4*)&xb[(size_t)row * KP + c0] = *(uint4*)o;
}

// ---------------------------------------------------------------------------
// CSR build: deg -> exclusive-scan offsets -> cursor fill, packed records
// ---------------------------------------------------------------------------
__global__ __launch_bounds__(256) void k_zero(int* __restrict__ p, int n)
{
    int i = blockIdx.x * blockDim.x + threadIdx.x;
    if (i < n) p[i] = 0;
}

__global__ __launch_bounds__(256) void k_deg(
    const int* __restrict__ ei, int* __restrict__ deg, int E)
{
    int e = blockIdx.x * blockDim.x + threadIdx.x;
    if (e >= E) return;
    atomicAdd(&deg[ei[E + e]], 1);
}

__global__ __launch_bounds__(256) void k_scan1(
    const int* __restrict__ deg, int* __restrict__ offsets,
    int* __restrict__ bsum, int n)
{
    __shared__ int sh[256];
    int tid = threadIdx.x;
    int base = blockIdx.x * SCAN_B + tid * 8;
    int v[8], run = 0;
#pragma unroll
    for (int j = 0; j < 8; ++j) {
        int i = base + j;
        v[j] = (i < n) ? deg[i] : 0;
        run += v[j];
        v[j] = run;
    }
    sh[tid] = run;
    __syncthreads();
    for (int off = 1; off < 256; off <<= 1) {
        int t = (tid >= off) ? sh[tid - off] : 0;
        __syncthreads();
        sh[tid] += t;
        __syncthreads();
    }
    int excl = sh[tid] - run;
#pragma unroll
    for (int j = 0; j < 8; ++j) {
        int i = base + j;
        if (i < n) offsets[i + 1] = excl + v[j];
    }
    if (tid == 0) bsum[blockIdx.x] = sh[255];
}

__global__ void k_scan2(int* __restrict__ bsum, int nb, int* __restrict__ offsets)
{
    if (threadIdx.x == 0 && blockIdx.x == 0) {
        int run = 0;
        for (int b = 0; b < nb; ++b) { int t = bsum[b]; bsum[b] = run; run += t; }
        offsets[0] = 0;
    }
}

__global__ __launch_bounds__(256) void k_scan3(
    const int* __restrict__ deg, int* __restrict__ offsets,
    const int* __restrict__ bsum, int* __restrict__ cursor, int n)
{
    int i = blockIdx.x * blockDim.x + threadIdx.x;
    if (i >= n) return;
    int fin = offsets[i + 1] + bsum[i / SCAN_B];
    offsets[i + 1] = fin;
    cursor[i] = fin - deg[i];
}

__global__ __launch_bounds__(256) void k_fill(
    const int* __restrict__ ei, const int* __restrict__ ea,
    int* __restrict__ cursor, int* __restrict__ edgerec, int E)
{
    int e = blockIdx.x * blockDim.x + threadIdx.x;
    if (e >= E) return;
    int dst = ei[E + e];
    int pos = atomicAdd(&cursor[dst], 1);
    int src = ei[e];
    int td  = ea[2 * e] * 3 + ea[2 * e + 1];
    edgerec[pos] = src | (td << 20);
}

// ---------------------------------------------------------------------------
// Gather-side aggregation:
// Ab[v] = bf16( h[v] + embc[0] + sum_{e: dst=v} ( h[src_e] + embc[td_e] ) )
// ---------------------------------------------------------------------------
__global__ __launch_bounds__(256) void k_aggr(
    const unsigned short* __restrict__ h,
    const int* __restrict__ offsets, const int* __restrict__ edgerec,
    const float* __restrict__ embc,
    unsigned short* __restrict__ Ab, int n, int Mpad)
{
    int idx = blockIdx.x * blockDim.x + threadIdx.x;
    if (idx >= Mpad * (KP / 8)) return;
    int v = idx / (KP / 8), c0 = (idx % (KP / 8)) * 8;
    unsigned short* outp = &Ab[(size_t)v * KP + c0];
    if (v >= n) {
        *(uint4*)outp = make_uint4(0, 0, 0, 0);
        return;
    }
    float acc[8];
    u16x8 hv = *(const u16x8*)&h[(size_t)v * KP + c0];
    const float* e0 = embc + c0;
#pragma unroll
    for (int j = 0; j < 8; ++j) acc[j] = b2f(hv[j]) + e0[j];

    int beg = offsets[v], end = offsets[v + 1];
    for (int e = beg; e < end; ++e) {
        int rec = edgerec[e];
        int src = rec & 0xFFFFF;
        int td  = rec >> 20;
        u16x8 hs = *(const u16x8*)&h[(size_t)src * KP + c0];
        const float* ee = embc + td * KP + c0;
#pragma unroll
        for (int j = 0; j < 8; ++j) acc[j] += b2f(hs[j]) + ee[j];
    }
    unsigned short o[8];
#pragma unroll
    for (int j = 0; j < 8; ++j) o[j] = f2b(acc[j]);
    *(uint4*)outp = *(uint4*)o;
}

// ---------------------------------------------------------------------------
// Wt[n*Kpad + k] = bf16(W[k*cols + n]) if in range else 0
// ---------------------------------------------------------------------------
__global__ __launch_bounds__(256) void k_cvtW(
    const float* __restrict__ W, unsigned short* __restrict__ Wt,
    int rows, int cols, int Kpad, int Npad)
{
    int t = blockIdx.x * blockDim.x + threadIdx.x;
    if (t >= Npad * Kpad) return;
    int nn = t / Kpad, k = t % Kpad;
    float v = (k < rows && nn < cols) ? W[(size_t)k * cols + nn] : 0.f;
    Wt[t] = f2b(v);
}

// ---------------------------------------------------------------------------
// bf16 MFMA GEMM, grid-parallel + XCD-swizzled + XOR-swizzled LDS:
// Staging lane L fetches row (L>>2), k-chunk ((L&3) ^ ((L>>3)&3)) -- the 4
// lanes of a row cover the same contiguous 64B (coalesced, 16 lines/wave),
// while chunk (r,c) lands at LDS slot 4r + (c ^ ((r>>1)&3)). Fragment
// ds_read_b128 phases then hit bank-group positions 0,4,1,5,2,6,3,7 -- a
// perfect minimum sweep (2-way aliasing only, which is free).
// Epilogue bounces accumulators through LDS for coalesced uint4 stores.
// C = relu(A @ Bt^T + bias). A [Mpad x K] rm bf16, Bt [N x K] rm bf16.
// ---------------------------------------------------------------------------
__global__ __launch_bounds__(256) void k_gemm(
    const unsigned short* __restrict__ Ag, const unsigned short* __restrict__ Bg,
    const float* __restrict__ bias, int bias_n,
    unsigned short* __restrict__ C, int ldc, int store_cols,
    int K, int npass, int MT)
{
    __shared__ unsigned short smem[8192];   // 16 KB: sA [0,4096), sB [4096,8192)

    int tid  = threadIdx.x;
    int lane = tid & 63, wave = tid >> 6;

    // XCD-swizzle: same panel -> same XCD for all npass column tiles
    int l    = blockIdx.x;
    int xcd  = l & 7;
    int j    = l >> 3;
    int ncol = j % npass;
    int panel= (j / npass) * 8 + xcd;
    if (panel >= MT) return;
    int m0 = panel * 128;

    int wm = (wave >> 1) * 64, wn = (wave & 1) * 64;
    int fr = lane & 15, fq = lane >> 4;          // fragment row / k-chunk
    int colq = lane & 15, rq = (lane >> 4) * 4;  // epilogue C/D mapping

    const unsigned short* Abase = Ag + (size_t)m0 * K;
    const unsigned short* Bbase = Bg + (size_t)ncol * 128 * K;

    // staging: chunk-slot ids for the two issues; global k-chunk is XOR-swizzled
    int c0 = tid, c1 = 256 + tid;
    size_t aoff0 = (size_t)(c0 >> 2) * K + 8 * ((c0 & 3) ^ ((c0 >> 3) & 3));
    size_t aoff1 = (size_t)(c1 >> 2) * K + 8 * ((c1 & 3) ^ ((c1 >> 3) & 3));

    // fragment LDS offsets (in shorts): slot(r, q) = 4r + (q ^ ((r&15)>>1 &3))
    int fswz = 8 * (fq ^ ((fr >> 1) & 3));

    f32x4 acc[4][4];
#pragma unroll
    for (int i = 0; i < 4; ++i)
#pragma unroll
        for (int jj = 0; jj < 4; ++jj)
            acc[i][jj] = (f32x4){0.f, 0.f, 0.f, 0.f};

    for (int k0 = 0; k0 < K; k0 += 32) {
        GLD_LDS16(Abase + aoff0 + k0, &smem[c0 * 8]);
        GLD_LDS16(Abase + aoff1 + k0, &smem[c1 * 8]);
        GLD_LDS16(Bbase + aoff0 + k0, &smem[4096 + c0 * 8]);
        GLD_LDS16(Bbase + aoff1 + k0, &smem[4096 + c1 * 8]);
        __syncthreads();

        bf16x8 af[4], bfv[4];
#pragma unroll
        for (int i = 0; i < 4; ++i) {
            af[i]  = *(const bf16x8*)&smem[(wm + i * 16 + fr) * 32 + fswz];
            bfv[i] = *(const bf16x8*)&smem[4096 + (wn + i * 16 + fr) * 32 + fswz];
        }
#pragma unroll
        for (int i = 0; i < 4; ++i)
#pragma unroll
            for (int jj = 0; jj < 4; ++jj)
                acc[i][jj] = __builtin_amdgcn_mfma_f32_16x16x32_bf16(
                    af[i], bfv[jj], acc[i][jj], 0, 0, 0);
        __syncthreads();
    }

    // ---- epilogue: bias + relu + bf16, LDS bounce for coalesced stores ----
#pragma unroll
    for (int ch = 0; ch < 2; ++ch) {
        if ((wn >> 6) == ch) {              // waves owning this 64-col half
#pragma unroll
            for (int jj = 0; jj < 4; ++jj) {
                int lc  = jj * 16 + colq;                  // 0..63
                int col = ncol * 128 + wn + jj * 16 + colq;
                float bv = (col < bias_n) ? bias[col] : 0.f;
#pragma unroll
                for (int i = 0; i < 4; ++i) {
                    int rbase = wm + i * 16 + rq;
#pragma unroll
                    for (int r = 0; r < 4; ++r) {
                        float v = fmaxf(acc[i][jj][r] + bv, 0.f);
                        smem[(rbase + r) * 64 + lc] = f2b(v);
                    }
                }
            }
        }
        __syncthreads();
        int cbase = ncol * 128 + ch * 64;
        if (cbase < store_cols) {
#pragma unroll
            for (int i = 0; i < 4; ++i) {
                int idx = i * 256 + tid;        // 0..1023 uint4 chunks
                int row = idx >> 3, c8 = idx & 7;
                *(uint4*)&C[(size_t)(m0 + row) * ldc + cbase + c8 * 8] =
                    *(uint4*)&smem[row * 64 + c8 * 8];
            }
        }
        __syncthreads();
    }
}

// ---------------------------------------------------------------------------
// pool: g[gid] = sum of Hb rows (bf16, stride KP) with batch==gid (sorted)
// ---------------------------------------------------------------------------
__global__ __launch_bounds__(256) void k_pool(
    const unsigned short* __restrict__ H, const int* __restrict__ batch,
    float* __restrict__ g, int n)
{
    int gid = blockIdx.x;
    int lo = 0, hi = n;
    while (lo < hi) { int mid = (lo + hi) >> 1; if (batch[mid] < gid) lo = mid + 1; else hi = mid; }
    int start = lo;
    hi = n;
    while (lo < hi) { int mid = (lo + hi) >> 1; if (batch[mid] < gid + 1) lo = mid + 1; else hi = mid; }
    int end = lo;

    for (int f = threadIdx.x; f < NFEAT; f += blockDim.x) {
        float acc = 0.f;
        for (int v = start; v < end; ++v) acc += b2f(H[(size_t)v * KP + f]);
        g[(size_t)gid * NFEAT + f] = acc;
    }
}

// ---------------------------------------------------------------------------
// out = g @ Wfc + bfc   (2048x300 @ 300x300), fp32
// ---------------------------------------------------------------------------
__global__ __launch_bounds__(256) void k_final(
    const float* __restrict__ g, const float* __restrict__ Wfc,
    const float* __restrict__ bfc, float* __restrict__ out)
{
    int idx = blockIdx.x * blockDim.x + threadIdx.x;
    if (idx >= NGRAPH * NFEAT) return;
    int r = idx / NFEAT, c = idx % NFEAT;
    float acc = bfc[c];
    for (int k = 0; k < NFEAT; ++k)
        acc = fmaf(g[(size_t)r * NFEAT + k], Wfc[(size_t)k * NFEAT + c], acc);
    out[idx] = acc;
}

extern "C" void kernel_launch(void* const* d_in, const int* in_sizes, int n_in,
                              void* d_out, int out_size, void* d_ws, size_t ws_size,
                              hipStream_t stream)
{
    const float* x    = (const float*)d_in[0];
    const int*   ei   = (const int*)  d_in[1];
    const int*   ea   = (const int*)  d_in[2];
    const int*   batch= (const int*)  d_in[3];
    const float* emb1 = (const float*)d_in[4];
    const float* emb2 = (const float*)d_in[5];
    const float* W1   = (const float*)d_in[6];
    const float* b1   = (const float*)d_in[7];
    const float* W2   = (const float*)d_in[8];
    const float* b2   = (const float*)d_in[9];
    const float* Wfc  = (const float*)d_in[10];
    const float* bfc  = (const float*)d_in[11];
    float* out = (float*)d_out;

    int n = in_sizes[0] / NFEAT;   // 100000
    int E = in_sizes[1] / 2;       // 200000
    int MT   = (n + 127) / 128;    // 782
    int Mpad = MT * 128;           // 100096
    int MT8  = ((MT + 7) / 8) * 8; // 784 (XCD-swizzle padding)

    // ---- workspace layout ----
    char* p = (char*)d_ws;
    auto take = [&](size_t bytes) { char* r = p; p += (bytes + 255) & ~(size_t)255; return r; };
    unsigned short* T    = (unsigned short*)take((size_t)Mpad * N1P * 2); // 128.1 MB
    unsigned short* xb   = T;                                             // overlay (dead before T)
    unsigned short* Ab   = (unsigned short*)take((size_t)Mpad * KP * 2);  // 64.06 MB
    unsigned short* Hb   = (unsigned short*)take((size_t)Mpad * KP * 2);  // 64.06 MB
    unsigned short* Wt1  = (unsigned short*)take((size_t)N1P * KP * 2);
    unsigned short* Wt2  = (unsigned short*)take((size_t)N2P * N1P * 2);
    float*          embc = (float*)take((size_t)NTD * KP * 4);
    float*          g    = (float*)take((size_t)NGRAPH * NFEAT * 4);
    int*            deg  = (int*)take((size_t)n * 4);
    int*            offs = (int*)take((size_t)(n + 1) * 4);
    int*            curs = (int*)take((size_t)n * 4);
    int*            erec = (int*)take((size_t)E * 4);
    int*            bsum = (int*)take(256 * 4);

    dim3 blk(256);
    int chunkThreads = Mpad * (KP / 8);
    int chunkBlocks  = (chunkThreads + 255) / 256;
    int nb = (n + SCAN_B - 1) / SCAN_B;

    // ---- one-time prep (per call) ----
    k_cvtW<<<(N1P * KP + 255) / 256, blk, 0, stream>>>(W1, Wt1, NFEAT, 600, KP, N1P);
    k_cvtW<<<(N2P * N1P + 255) / 256, blk, 0, stream>>>(W2, Wt2, 600, NFEAT, N1P, N2P);
    k_embc<<<(NTD * KP + 255) / 256, blk, 0, stream>>>(emb1, emb2, embc);
    k_cvtX<<<chunkBlocks, blk, 0, stream>>>(x, xb, n, Mpad);

    // ---- CSR build ----
    k_zero <<<(n + 255) / 256, blk, 0, stream>>>(deg, n);
    k_deg  <<<(E + 255) / 256, blk, 0, stream>>>(ei, deg, E);
    k_scan1<<<nb, blk, 0, stream>>>(deg, offs, bsum, n);
    k_scan2<<<1, 64, 0, stream>>>(bsum, nb, offs);
    k_scan3<<<(n + 255) / 256, blk, 0, stream>>>(deg, offs, bsum, curs, n);
    k_fill <<<(E + 255) / 256, blk, 0, stream>>>(ei, ea, curs, erec, E);

    // ---- layer 1 ----
    k_aggr<<<chunkBlocks, blk, 0, stream>>>(xb, offs, erec, embc, Ab, n, Mpad);
    k_gemm<<<MT8 * (N1P / 128), blk, 0, stream>>>(Ab, Wt1, b1, 600, T, N1P, N1P, KP, N1P / 128, MT);
    k_gemm<<<MT8 * (N2P / 128), blk, 0, stream>>>(T, Wt2, b2, NFEAT, Hb, KP, KP, N1P, N2P / 128, MT);

    // ---- layer 2 ----
    k_aggr<<<chunkBlocks, blk, 0, stream>>>(Hb, offs, erec, embc, Ab, n, Mpad);
    k_gemm<<<MT8 * (N1P / 128), blk, 0, stream>>>(Ab, Wt1, b1, 600, T, N1P, N1P, KP, N1P / 128, MT);
    k_gemm<<<MT8 * (N2P / 128), blk, 0, stream>>>(T, Wt2, b2, NFEAT, Hb, KP, KP, N1P, N2P / 128, MT);

    // ---- pool + final ----
    k_pool <<<NGRAPH, blk, 0, stream>>>(Hb, batch, g, n);
    k_final<<<(NGRAPH * NFEAT + 255) / 256, blk, 0, stream>>>(g, Wfc, bfc, out);
}